// Round 1
// baseline (627.312 us; speedup 1.0000x reference)
//
#include <hip/hip_runtime.h>

#define TDIM 2048

typedef __attribute__((ext_vector_type(8))) short short8;
typedef __attribute__((ext_vector_type(4))) short short4v;
typedef __attribute__((ext_vector_type(4))) float float4v;

__device__ __forceinline__ float sigf(float x) { return 1.0f / (1.0f + __expf(-x)); }

__device__ __forceinline__ unsigned short f2bf_rne(float f) {
    unsigned u = __float_as_uint(f);
    unsigned r = (u + 0x7fffu + ((u >> 16) & 1u)) >> 16;
    return (unsigned short)r;
}
__device__ __forceinline__ float bf2f(unsigned short h) {
    return __uint_as_float(((unsigned)h) << 16);
}
struct bfpair { short hi, lo; };
__device__ __forceinline__ bfpair cvt_split(float x) {
    bfpair p;
    unsigned short h = f2bf_rne(x);
    p.hi = (short)h;
    p.lo = (short)f2bf_rne(x - bf2f(h));
    return p;
}
__device__ __forceinline__ void split4(float4 v, short4v& hi, short4v& lo) {
    bfpair a = cvt_split(v.x), b = cvt_split(v.y), c = cvt_split(v.z), d = cvt_split(v.w);
    short4v h = {a.hi, b.hi, c.hi, d.hi};
    short4v l = {a.lo, b.lo, c.lo, d.lo};
    hi = h; lo = l;
}

#define RED16(v) { v += __shfl_xor(v, 1); v += __shfl_xor(v, 2); \
                   v += __shfl_xor(v, 4); v += __shfl_xor(v, 8); }

__device__ __forceinline__ float dot4f(float4 a, float4 b) {
    return fmaf(a.w, b.w, fmaf(a.z, b.z, fmaf(a.y, b.y, a.x * b.x)));
}
// Sum across the 4 g-groups (lanes i, i+16, i+32, i+48) via gfx950 VALU
// permlane swaps — no LDS pipe, no lgkmcnt coupling with ds_read prefetch.
__device__ __forceinline__ float red4g(float v) {
    float a = v, b = v;
    asm("v_permlane16_swap_b32 %0, %1" : "+v"(a), "+v"(b));
    float s = a + b;                 // v + shfl_xor(v,16)
    float c = s, d = s;
    asm("v_permlane32_swap_b32 %0, %1" : "+v"(c), "+v"(d));
    return c + d;                    // + shfl_xor(.,32)
}

// LDS row layout (shorts): 8 k-groups x [8 hi | 8 lo] + 8 pad = 136 shorts
#define LROW 136

// ---------------------------------------------------------------------------
// prep_w: pre-split concatenated W (200x256, rows>=200 zero-padded to 208)
// into the proj LDS image: [kc 0..3][row 0..207][gg 0..7][hi8|lo8].
// 6656 units of 16 shorts.
// ---------------------------------------------------------------------------
__global__ __launch_bounds__(256) void prep_w_kernel(
    const float* __restrict__ Wq, const float* __restrict__ Wk, const float* __restrict__ Wv,
    const float* __restrict__ Wbw, const float* __restrict__ Waw,
    short* __restrict__ wimg)
{
    int u = blockIdx.x * 256 + threadIdx.x;
    if (u >= 6656) return;
    int kc = u / 1664, rem = u % 1664;
    int rr = rem >> 3, gg = rem & 7;
    const float* wrow = nullptr;
    if (rr < 64)       wrow = Wq  + (size_t)rr * 256;
    else if (rr < 128) wrow = Wk  + (size_t)(rr - 64) * 256;
    else if (rr < 192) wrow = Wv  + (size_t)(rr - 128) * 256;
    else if (rr < 196) wrow = Wbw + (size_t)(rr - 192) * 256;
    else if (rr < 200) wrow = Waw + (size_t)(rr - 196) * 256;
    short* dst = wimg + (size_t)u * 16;
#pragma unroll
    for (int s = 0; s < 8; ++s) {
        float v = wrow ? wrow[kc * 64 + gg * 8 + s] : 0.0f;
        bfpair p = cvt_split(v);
        dst[s] = p.hi; dst[8 + s] = p.lo;
    }
}

// prep_ow: same for out_w (192x64): [row 0..191][gg 0..7][hi8|lo8], 1536 units.
__global__ __launch_bounds__(256) void prep_ow_kernel(
    const float* __restrict__ ow, short* __restrict__ owimg)
{
    int u = blockIdx.x * 256 + threadIdx.x;
    if (u >= 1536) return;
    int rr = u >> 3, gg = u & 7;
    short* dst = owimg + (size_t)u * 16;
#pragma unroll
    for (int s = 0; s < 8; ++s) {
        bfpair p = cvt_split(ow[(size_t)rr * 64 + gg * 8 + s]);
        dst[s] = p.hi; dst[8 + s] = p.lo;
    }
}

// ---------------------------------------------------------------------------
// Kernel A: fused projection GEMM (split-bf16 MFMA) + LN/L2norm/sigmoid epilogue
// ---------------------------------------------------------------------------
__global__ __launch_bounds__(256, 2) void proj_kernel(
    const float* __restrict__ x, const float* __restrict__ curv, const float* __restrict__ ent,
    const short* __restrict__ wimg,
    const float* __restrict__ Wbb, const float* __restrict__ Wab,
    const float* __restrict__ cw, const float* __restrict__ ew,
    const float* __restrict__ lnqw, const float* __restrict__ lnqb,
    const float* __restrict__ lnkw, const float* __restrict__ lnkb,
    float* __restrict__ q_ws, float* __restrict__ k_ws, float* __restrict__ v_ws,
    float* __restrict__ beta_ws, float* __restrict__ alpha_ws)
{
    __shared__ __align__(16) short xsh[64 * LROW];
    __shared__ __align__(16) short wsh[208 * LROW];

    const int tid = threadIdx.x;
    const int lane = tid & 63, wv = tid >> 6;
    const int row0 = blockIdx.x * 64;

    float4v acc[13];
#pragma unroll
    for (int cc = 0; cc < 13; ++cc) acc[cc] = (float4v){0.f, 0.f, 0.f, 0.f};

    for (int kc = 0; kc < 4; ++kc) {
        __syncthreads();
        // stage X chunk: 64 rows x 64 k (split in-kernel; each row converted once)
#pragma unroll
        for (int it = 0; it < 4; ++it) {
            int f = it * 256 + tid;
            int rr = f >> 4, c4 = f & 15;
            float4 xv = *(const float4*)&x[(size_t)(row0 + rr) * 256 + kc * 64 + c4 * 4];
            short4v hi, lo;
            split4(xv, hi, lo);
            short* ph = &xsh[rr * LROW + (c4 >> 1) * 16 + (c4 & 1) * 4];
            *(short4v*)ph = hi;
            *(short4v*)(ph + 8) = lo;
        }
        // stage W chunk: pure copy from pre-split image (3328 x 16B)
        {
            const int4* wsrc = (const int4*)(wimg + (size_t)kc * 26624);
#pragma unroll
            for (int it = 0; it < 13; ++it) {
                int f = it * 256 + tid;
                int4 tv = wsrc[f];
                int row = f >> 4, idx = f & 15;
                *(int4*)&wsh[row * LROW + (idx >> 1) * 16 + (idx & 1) * 8] = tv;
            }
        }
        __syncthreads();
#pragma unroll
        for (int ks = 0; ks < 2; ++ks) {
            const int rowA = wv * 16 + (lane & 15);
            const int g4 = ks * 4 + (lane >> 4);
            short8 ah = *(const short8*)&xsh[rowA * LROW + g4 * 16];
            short8 al = *(const short8*)&xsh[rowA * LROW + g4 * 16 + 8];
#pragma unroll
            for (int nt = 0; nt < 13; ++nt) {
                const int rowB = nt * 16 + (lane & 15);
                short8 bh = *(const short8*)&wsh[rowB * LROW + g4 * 16];
                short8 bl = *(const short8*)&wsh[rowB * LROW + g4 * 16 + 8];
                acc[nt] = __builtin_amdgcn_mfma_f32_16x16x32_bf16(ah, bh, acc[nt], 0, 0, 0);
                acc[nt] = __builtin_amdgcn_mfma_f32_16x16x32_bf16(ah, bl, acc[nt], 0, 0, 0);
                acc[nt] = __builtin_amdgcn_mfma_f32_16x16x32_bf16(al, bh, acc[nt], 0, 0, 0);
            }
        }
    }

    // Epilogue. C/D layout: col = lane&15, row = (lane>>4)*4 + reg.
    const int c = lane & 15, lq = lane >> 4;
    const float lnqw_c = lnqw[c], lnqb_c = lnqb[c];
    const float lnkw_c = lnkw[c], lnkb_c = lnkb[c];
#pragma unroll
    for (int j = 0; j < 4; ++j) {
        const int grow = row0 + wv * 16 + lq * 4 + j;
        const int n = grow >> 11, t = grow & 2047;
#pragma unroll
        for (int h = 0; h < 4; ++h) {
            float y = acc[h][j];
            float s = y;  RED16(s);
            float s2 = y * y;  RED16(s2);
            float mean = s * 0.0625f;
            float var = s2 * 0.0625f - mean * mean;
            float inv = rsqrtf(var + 1e-5f);
            q_ws[((size_t)(n * 4 + h) * TDIM + t) * 16 + c] = (y - mean) * inv * lnqw_c + lnqb_c;
        }
#pragma unroll
        for (int h = 0; h < 4; ++h) {
            float y = acc[4 + h][j];
            float s = y;  RED16(s);
            float s2 = y * y;  RED16(s2);
            float mean = s * 0.0625f;
            float var = s2 * 0.0625f - mean * mean;
            float inv = rsqrtf(var + 1e-5f);
            float kn = (y - mean) * inv * lnkw_c + lnkb_c;
            float s3 = kn * kn;  RED16(s3);
            kn = kn / fmaxf(sqrtf(s3), 1e-12f);
            k_ws[((size_t)(n * 4 + h) * TDIM + t) * 16 + c] = kn;
        }
#pragma unroll
        for (int h = 0; h < 4; ++h)
            v_ws[((size_t)(n * 4 + h) * TDIM + t) * 16 + c] = acc[8 + h][j];
        float yb = acc[12][j];
        if (c < 4) {
            float Kv = fminf(fabsf(curv[n >> 4]), 10.0f);
            beta_ws[(size_t)(n * 4 + c) * TDIM + t] = sigf(sigf(yb + Wbb[c]) + Kv * cw[c]);
        } else if (c < 8) {
            int h = c - 4;
            float Sv = fminf(fmaxf(ent[n >> 4], 0.0f), 5.0f);
            alpha_ws[(size_t)(n * 4 + h) * TDIM + t] = sigf(sigf(yb + Wab[h]) + Sv * ew[h]);
        }
    }
}

// ---------------------------------------------------------------------------
// Kernel B: delta-rule scan, 1 wave/chain. Lane: row i=lane&15, col-quad
// g=lane>>4 (M[i][4g..4g+3]). 2-step-stale reassociation:
//   p_t = u'_t + w_{t-2} C2_t + w_{t-1} C_t,  u'_t = M_{t-3} k_t
//   o_t = r'_t + w_{t-2} E2_t + w_{t-1} e_t + w_t d_t,  r'_t = M_{t-3} q_t
// Table stores alpha-prescaled aC = al*C, aC2 = al*C2 so the critical
// recurrence is ONE fma: w0 = fmaf(-aC1, w1, r) with r off-chain.
// up/rp reductions use permlane16/32_swap (VALU) — no LDS-pipe shfl.
// ---------------------------------------------------------------------------
__global__ __launch_bounds__(64) void scan_kernel(
    const float* __restrict__ q_ws, const float* __restrict__ k_ws, const float* __restrict__ v_ws,
    const float* __restrict__ beta_ws, const float* __restrict__ alpha_ws,
    float* __restrict__ o_ws)
{
    __shared__ __align__(16) float ks[128 * 16], qs[128 * 16], bvs[128 * 16];
    __shared__ __align__(16) float tbl[128 * 8];
    __shared__ __align__(16) float os[64 * 16];
    const int tid = threadIdx.x;
    const int cid = blockIdx.x;
    const int i = tid & 15, g = tid >> 4;
    const float* kb = k_ws + (size_t)cid * TDIM * 16;
    const float* qb = q_ws + (size_t)cid * TDIM * 16;
    const float* vb = v_ws + (size_t)cid * TDIM * 16;
    const float* bb = beta_ws + (size_t)cid * TDIM;
    const float* ab = alpha_ws + (size_t)cid * TDIM;
    float* obp = o_ws + (size_t)cid * TDIM * 16;

    // zero LDS so circular reads before t=0 are clean zeros (not NaN garbage)
    for (int f = tid; f < 128 * 16; f += 64) { ks[f] = 0.f; qs[f] = 0.f; bvs[f] = 0.f; }
    for (int f = tid; f < 128 * 8; f += 64) tbl[f] = 0.f;
    __syncthreads();

    float4 kr[4], qr[4], vr[4]; float be = 0.f, alp = 0.f;
    auto load_stage = [&](int s) {
        size_t t0 = (size_t)s * 64 + tid;   // overruns at s=32 stay in ws (finite)
        const float4* kp = (const float4*)(kb + t0 * 16);
        const float4* qp = (const float4*)(qb + t0 * 16);
        const float4* vp = (const float4*)(vb + t0 * 16);
#pragma unroll
        for (int j = 0; j < 4; ++j) { kr[j] = kp[j]; qr[j] = qp[j]; vr[j] = vp[j]; }
        be = bb[t0]; alp = ab[t0];
    };
    auto commit_stage = [&](int s) {
        int r = (s & 1) * 64 + tid;
#pragma unroll
        for (int j = 0; j < 4; ++j) {
            *(float4*)&ks[r * 16 + 4 * j] = kr[j];
            *(float4*)&qs[r * 16 + 4 * j] = qr[j];
            float4 bv4 = make_float4(be * vr[j].x, be * vr[j].y, be * vr[j].z, be * vr[j].w);
            *(float4*)&bvs[r * 16 + 4 * j] = bv4;
        }
    };
    auto table_pass = [&](int s) {
        int r0 = (s & 1) * 64 + tid;
        int rm1 = (r0 - 1) & 127, rm2 = (r0 - 2) & 127;
        float C = 0.f, C2 = 0.f, d = 0.f, e = 0.f, E2 = 0.f;
#pragma unroll
        for (int j = 0; j < 4; ++j) {
            float4 kt  = *(float4*)&ks[r0 * 16 + 4 * j];
            float4 km1 = *(float4*)&ks[rm1 * 16 + 4 * j];
            float4 km2 = *(float4*)&ks[rm2 * 16 + 4 * j];
            float4 qt  = *(float4*)&qs[r0 * 16 + 4 * j];
            C  += dot4f(km1, kt);
            C2 += dot4f(km2, kt);
            d  += dot4f(kt,  qt);
            e  += dot4f(km1, qt);
            E2 += dot4f(km2, qt);
        }
        // alpha-prescale the k-corrections; alp is live for this chunk & lane==row
        *(float4*)&tbl[r0 * 8] = make_float4(alp * C, alp * C2, d, e);
        *(float2*)&tbl[r0 * 8 + 4] = make_float2(E2, alp);
    };

    // chunk 0
    load_stage(0);
    commit_stage(0);
    __syncthreads();
    table_pass(0);
    __syncthreads();

    // persistent recurrence state
    float4 M4 = make_float4(0.f, 0.f, 0.f, 0.f);    // M[i][4g..4g+3], lags 2 steps
    float w1 = 0.f, w2 = 0.f;                        // w_{t-1}, w_{t-2}
    float4 k4m1 = make_float4(0.f, 0.f, 0.f, 0.f);   // k_{t-1} quad (for M update)
    float4 k4_0 = *(float4*)&ks[0 * 16 + 4 * g];
    float4 k4p1 = *(float4*)&ks[1 * 16 + 4 * g];
    float4 q4p1 = *(float4*)&qs[1 * 16 + 4 * g];
    float up_cur = 0.f, rp_cur = 0.f;                // u'_t, r'_t
    float4 ta0 = *(float4*)&tbl[0];
    float aC1_c = ta0.x, aC2_c = ta0.y, d_c = ta0.z, e_c = ta0.w;
    float2 tx0 = *(float2*)&tbl[4];
    float E2_c = tx0.x, al_c = tx0.y;
    float bv_c = bvs[i];

    int t = 0;
    auto step = [&]() {
        int rp2 = (t + 2) & 127, rp1 = (t + 1) & 127;
        float4 k4in = *(float4*)&ks[rp2 * 16 + 4 * g];
        float4 q4in = *(float4*)&qs[rp2 * 16 + 4 * g];
        float4 tain = *(float4*)&tbl[rp1 * 8];
        float2 txin = *(float2*)&tbl[rp1 * 8 + 4];
        float bvin = bvs[rp1 * 16 + i];
        // u'_{t+1}, r'_{t+1} from M_{t-2} (pre-update) — 1 iter of slack,
        // reduce is now VALU-only (permlane), ~40cy total
        float up = red4g(dot4f(M4, k4p1));
        float rp = red4g(dot4f(M4, q4p1));
        // lazy M update: M_{t-2} -> M_{t-1}
        M4.x = fmaf(w1, k4m1.x, M4.x);
        M4.y = fmaf(w1, k4m1.y, M4.y);
        M4.z = fmaf(w1, k4m1.z, M4.z);
        M4.w = fmaf(w1, k4m1.w, M4.w);
        // off-chain residue, then the 1-fma critical recurrence
        float r = fmaf(-aC2_c, w2, fmaf(-al_c, up_cur, bv_c));
        float w0 = fmaf(-aC1_c, w1, r);
        float o = fmaf(w0, d_c, fmaf(w1, e_c, fmaf(w2, E2_c, rp_cur)));
        if (g == 0) os[(t & 63) * 16 + i] = o;
        // rotate
        w2 = w1; w1 = w0;
        k4m1 = k4_0; k4_0 = k4p1; k4p1 = k4in;
        q4p1 = q4in;
        up_cur = up; rp_cur = rp;
        aC1_c = tain.x; aC2_c = tain.y; d_c = tain.z; e_c = tain.w;
        E2_c = txin.x; al_c = txin.y; bv_c = bvin;
        ++t;
    };

    for (int s = 0; s < 32; ++s) {
        load_stage(s + 1);                 // global loads land over next ~32 steps
#pragma unroll 4
        for (int u = 0; u < 32; ++u) step();
        commit_stage(s + 1);               // mid-chunk: vmcnt long satisfied
#pragma unroll 4
        for (int u = 0; u < 16; ++u) step();
        table_pass(s + 1);                 // needs commit done; rows t-1,t-2 intact
#pragma unroll 4
        for (int u = 0; u < 16; ++u) step();
        // flush o chunk (DS in-order: all 64 os rows written)
#pragma unroll
        for (int j = 0; j < 4; ++j) {
            float4 ov = *(float4*)&os[(tid * 4 + j) * 4];
            *(float4*)&obp[(size_t)s * 1024 + (tid * 4 + j) * 4] = ov;
        }
    }
}

// ---------------------------------------------------------------------------
// Kernel C: output projection (split-bf16 MFMA), W from pre-split image.
// ---------------------------------------------------------------------------
__global__ __launch_bounds__(256, 2) void outproj_kernel(
    const float* __restrict__ o_ws, const short* __restrict__ owimg,
    const float* __restrict__ ob, float* __restrict__ out)
{
    __shared__ __align__(16) short osh[64 * LROW];
    __shared__ __align__(16) short wsh[192 * LROW];
    const int tid = threadIdx.x;
    const int lane = tid & 63, wv = tid >> 6;
    const int row0 = blockIdx.x * 64;

    float4v acc[12];
#pragma unroll
    for (int cc = 0; cc < 12; ++cc) acc[cc] = (float4v){0.f, 0.f, 0.f, 0.f};

#pragma unroll
    for (int it = 0; it < 4; ++it) {
        int f = it * 256 + tid;
        int rr = f >> 4, c4 = f & 15;
        int grow = row0 + rr;
        int n = grow >> 11, t = grow & 2047;
        int h = c4 >> 2, d4 = c4 & 3;
        float4 xv = *(const float4*)&o_ws[((size_t)(n * 4 + h) * TDIM + t) * 16 + d4 * 4];
        short4v hi, lo;
        split4(xv, hi, lo);
        short* ph = &osh[rr * LROW + (c4 >> 1) * 16 + (c4 & 1) * 4];
        *(short4v*)ph = hi;
        *(short4v*)(ph + 8) = lo;
    }
    {
        const int4* wsrc = (const int4*)owimg;
#pragma unroll
        for (int it = 0; it < 12; ++it) {
            int f = it * 256 + tid;
            int4 tv = wsrc[f];
            int row = f >> 4, idx = f & 15;
            *(int4*)&wsh[row * LROW + (idx >> 1) * 16 + (idx & 1) * 8] = tv;
        }
    }
    __syncthreads();

#pragma unroll
    for (int ks = 0; ks < 2; ++ks) {
        const int rowA = wv * 16 + (lane & 15);
        const int g4 = ks * 4 + (lane >> 4);
        short8 ah = *(const short8*)&osh[rowA * LROW + g4 * 16];
        short8 al = *(const short8*)&osh[rowA * LROW + g4 * 16 + 8];
#pragma unroll
        for (int nt = 0; nt < 12; ++nt) {
            const int rowB = nt * 16 + (lane & 15);
            short8 bh = *(const short8*)&wsh[rowB * LROW + g4 * 16];
            short8 bl = *(const short8*)&wsh[rowB * LROW + g4 * 16 + 8];
            acc[nt] = __builtin_amdgcn_mfma_f32_16x16x32_bf16(ah, bh, acc[nt], 0, 0, 0);
            acc[nt] = __builtin_amdgcn_mfma_f32_16x16x32_bf16(ah, bl, acc[nt], 0, 0, 0);
            acc[nt] = __builtin_amdgcn_mfma_f32_16x16x32_bf16(al, bh, acc[nt], 0, 0, 0);
        }
    }

    const int c = lane & 15, lq = lane >> 4;
#pragma unroll
    for (int nt = 0; nt < 12; ++nt) {
        float bias = ob[nt * 16 + c];
#pragma unroll
        for (int j = 0; j < 4; ++j) {
            int grow = row0 + wv * 16 + lq * 4 + j;
            int n = grow >> 11, t = grow & 2047;
            int b = n >> 4, p = n & 15;
            out[((size_t)(b * TDIM + t) * 16 + p) * 192 + nt * 16 + c] = acc[nt][j] + bias;
        }
    }
}

extern "C" void kernel_launch(void* const* d_in, const int* in_sizes, int n_in,
                              void* d_out, int out_size, void* d_ws, size_t ws_size,
                              hipStream_t stream) {
    (void)in_sizes; (void)n_in; (void)out_size; (void)ws_size;
    const float* x    = (const float*)d_in[0];
    const float* curv = (const float*)d_in[1];
    const float* ent  = (const float*)d_in[2];
    const float* Wq   = (const float*)d_in[3];
    const float* Wk   = (const float*)d_in[4];
    const float* Wv   = (const float*)d_in[5];
    const float* Wbw  = (const float*)d_in[6];
    const float* Wbb  = (const float*)d_in[7];
    const float* Waw  = (const float*)d_in[8];
    const float* Wab  = (const float*)d_in[9];
    const float* cw   = (const float*)d_in[10];
    const float* ew   = (const float*)d_in[11];
    const float* ow   = (const float*)d_in[12];
    const float* ob   = (const float*)d_in[13];
    const float* lnqw = (const float*)d_in[14];
    const float* lnqb = (const float*)d_in[15];
    const float* lnkw = (const float*)d_in[16];
    const float* lnkb = (const float*)d_in[17];
    float* out = (float*)d_out;

    float* ws = (float*)d_ws;
    float* q_ws     = ws;                    // 8,388,608 floats
    float* k_ws     = q_ws + 8388608;
    float* v_ws     = k_ws + 8388608;
    float* beta_ws  = v_ws + 8388608;        // 524,288
    float* alpha_ws = beta_ws + 524288;
    float* o_ws     = alpha_ws + 524288;     // 8,388,608

    // Overlays (no extra ws): wimg lives at o_ws head (dead before scan writes
    // o_ws); owimg lives at q_ws head (written after scan, q_ws then dead).
    short* wimg  = (short*)o_ws;             // 106,496 shorts
    short* owimg = (short*)q_ws;             // 24,576 shorts

    prep_w_kernel<<<26, 256, 0, stream>>>(Wq, Wk, Wv, Wbw, Waw, wimg);
    proj_kernel<<<2048, 256, 0, stream>>>(x, curv, ent, wimg, Wbb, Wab,
                                          cw, ew, lnqw, lnqb, lnkw, lnkb,
                                          q_ws, k_ws, v_ws, beta_ws, alpha_ws);
    scan_kernel<<<256, 64, 0, stream>>>(q_ws, k_ws, v_ws, beta_ws, alpha_ws, o_ws);
    prep_ow_kernel<<<6, 256, 0, stream>>>(ow, owimg);
    outproj_kernel<<<2048, 256, 0, stream>>>(o_ws, owimg, ob, out);
}

// Round 2
// 495.170 us; speedup vs baseline: 1.2669x; 1.2669x over previous
//
#include <hip/hip_runtime.h>

#define TDIM 2048
#define SEG 16
#define SEGLEN 128

typedef __attribute__((ext_vector_type(8))) short short8;
typedef __attribute__((ext_vector_type(4))) short short4v;
typedef __attribute__((ext_vector_type(4))) float float4v;

__device__ __forceinline__ float sigf(float x) { return 1.0f / (1.0f + __expf(-x)); }

__device__ __forceinline__ unsigned short f2bf_rne(float f) {
    unsigned u = __float_as_uint(f);
    unsigned r = (u + 0x7fffu + ((u >> 16) & 1u)) >> 16;
    return (unsigned short)r;
}
__device__ __forceinline__ float bf2f(unsigned short h) {
    return __uint_as_float(((unsigned)h) << 16);
}
struct bfpair { short hi, lo; };
__device__ __forceinline__ bfpair cvt_split(float x) {
    bfpair p;
    unsigned short h = f2bf_rne(x);
    p.hi = (short)h;
    p.lo = (short)f2bf_rne(x - bf2f(h));
    return p;
}
__device__ __forceinline__ void split4(float4 v, short4v& hi, short4v& lo) {
    bfpair a = cvt_split(v.x), b = cvt_split(v.y), c = cvt_split(v.z), d = cvt_split(v.w);
    short4v h = {a.hi, b.hi, c.hi, d.hi};
    short4v l = {a.lo, b.lo, c.lo, d.lo};
    hi = h; lo = l;
}

#define RED16(v) { v += __shfl_xor(v, 1); v += __shfl_xor(v, 2); \
                   v += __shfl_xor(v, 4); v += __shfl_xor(v, 8); }

__device__ __forceinline__ float dot4f(float4 a, float4 b) {
    return fmaf(a.w, b.w, fmaf(a.z, b.z, fmaf(a.y, b.y, a.x * b.x)));
}
// sum across the 4 g-groups (lanes i, i+16, i+32, i+48); broadcast to all
__device__ __forceinline__ float red4g(float v) {
    v += __shfl_xor(v, 16);
    v += __shfl_xor(v, 32);
    return v;
}

// LDS row layout (shorts): 8 k-groups x [8 hi | 8 lo] + 8 pad = 136 shorts
#define LROW 136

// ---------------------------------------------------------------------------
// prep_w: pre-split concatenated W (200x256, rows>=200 zero-padded to 208)
// into the proj LDS image: [kc 0..3][row 0..207][gg 0..7][hi8|lo8].
// ---------------------------------------------------------------------------
__global__ __launch_bounds__(256) void prep_w_kernel(
    const float* __restrict__ Wq, const float* __restrict__ Wk, const float* __restrict__ Wv,
    const float* __restrict__ Wbw, const float* __restrict__ Waw,
    short* __restrict__ wimg)
{
    int u = blockIdx.x * 256 + threadIdx.x;
    if (u >= 6656) return;
    int kc = u / 1664, rem = u % 1664;
    int rr = rem >> 3, gg = rem & 7;
    const float* wrow = nullptr;
    if (rr < 64)       wrow = Wq  + (size_t)rr * 256;
    else if (rr < 128) wrow = Wk  + (size_t)(rr - 64) * 256;
    else if (rr < 192) wrow = Wv  + (size_t)(rr - 128) * 256;
    else if (rr < 196) wrow = Wbw + (size_t)(rr - 192) * 256;
    else if (rr < 200) wrow = Waw + (size_t)(rr - 196) * 256;
    short* dst = wimg + (size_t)u * 16;
#pragma unroll
    for (int s = 0; s < 8; ++s) {
        float v = wrow ? wrow[kc * 64 + gg * 8 + s] : 0.0f;
        bfpair p = cvt_split(v);
        dst[s] = p.hi; dst[8 + s] = p.lo;
    }
}

// prep_ow: same for out_w (192x64): [row 0..191][gg 0..7][hi8|lo8], 1536 units.
__global__ __launch_bounds__(256) void prep_ow_kernel(
    const float* __restrict__ ow, short* __restrict__ owimg)
{
    int u = blockIdx.x * 256 + threadIdx.x;
    if (u >= 1536) return;
    int rr = u >> 3, gg = u & 7;
    short* dst = owimg + (size_t)u * 16;
#pragma unroll
    for (int s = 0; s < 8; ++s) {
        bfpair p = cvt_split(ow[(size_t)rr * 64 + gg * 8 + s]);
        dst[s] = p.hi; dst[8 + s] = p.lo;
    }
}

// ---------------------------------------------------------------------------
// Kernel A: fused projection GEMM (split-bf16 MFMA) + LN/L2norm/sigmoid epilogue
// ---------------------------------------------------------------------------
__global__ __launch_bounds__(256, 2) void proj_kernel(
    const float* __restrict__ x, const float* __restrict__ curv, const float* __restrict__ ent,
    const short* __restrict__ wimg,
    const float* __restrict__ Wbb, const float* __restrict__ Wab,
    const float* __restrict__ cw, const float* __restrict__ ew,
    const float* __restrict__ lnqw, const float* __restrict__ lnqb,
    const float* __restrict__ lnkw, const float* __restrict__ lnkb,
    float* __restrict__ q_ws, float* __restrict__ k_ws, float* __restrict__ v_ws,
    float* __restrict__ beta_ws, float* __restrict__ alpha_ws)
{
    __shared__ __align__(16) short xsh[64 * LROW];
    __shared__ __align__(16) short wsh[208 * LROW];

    const int tid = threadIdx.x;
    const int lane = tid & 63, wv = tid >> 6;
    const int row0 = blockIdx.x * 64;

    float4v acc[13];
#pragma unroll
    for (int cc = 0; cc < 13; ++cc) acc[cc] = (float4v){0.f, 0.f, 0.f, 0.f};

    for (int kc = 0; kc < 4; ++kc) {
        __syncthreads();
#pragma unroll
        for (int it = 0; it < 4; ++it) {
            int f = it * 256 + tid;
            int rr = f >> 4, c4 = f & 15;
            float4 xv = *(const float4*)&x[(size_t)(row0 + rr) * 256 + kc * 64 + c4 * 4];
            short4v hi, lo;
            split4(xv, hi, lo);
            short* ph = &xsh[rr * LROW + (c4 >> 1) * 16 + (c4 & 1) * 4];
            *(short4v*)ph = hi;
            *(short4v*)(ph + 8) = lo;
        }
        {
            const int4* wsrc = (const int4*)(wimg + (size_t)kc * 26624);
#pragma unroll
            for (int it = 0; it < 13; ++it) {
                int f = it * 256 + tid;
                int4 tv = wsrc[f];
                int row = f >> 4, idx = f & 15;
                *(int4*)&wsh[row * LROW + (idx >> 1) * 16 + (idx & 1) * 8] = tv;
            }
        }
        __syncthreads();
#pragma unroll
        for (int ks = 0; ks < 2; ++ks) {
            const int rowA = wv * 16 + (lane & 15);
            const int g4 = ks * 4 + (lane >> 4);
            short8 ah = *(const short8*)&xsh[rowA * LROW + g4 * 16];
            short8 al = *(const short8*)&xsh[rowA * LROW + g4 * 16 + 8];
#pragma unroll
            for (int nt = 0; nt < 13; ++nt) {
                const int rowB = nt * 16 + (lane & 15);
                short8 bh = *(const short8*)&wsh[rowB * LROW + g4 * 16];
                short8 bl = *(const short8*)&wsh[rowB * LROW + g4 * 16 + 8];
                acc[nt] = __builtin_amdgcn_mfma_f32_16x16x32_bf16(ah, bh, acc[nt], 0, 0, 0);
                acc[nt] = __builtin_amdgcn_mfma_f32_16x16x32_bf16(ah, bl, acc[nt], 0, 0, 0);
                acc[nt] = __builtin_amdgcn_mfma_f32_16x16x32_bf16(al, bh, acc[nt], 0, 0, 0);
            }
        }
    }

    const int c = lane & 15, lq = lane >> 4;
    const float lnqw_c = lnqw[c], lnqb_c = lnqb[c];
    const float lnkw_c = lnkw[c], lnkb_c = lnkb[c];
#pragma unroll
    for (int j = 0; j < 4; ++j) {
        const int grow = row0 + wv * 16 + lq * 4 + j;
        const int n = grow >> 11, t = grow & 2047;
#pragma unroll
        for (int h = 0; h < 4; ++h) {
            float y = acc[h][j];
            float s = y;  RED16(s);
            float s2 = y * y;  RED16(s2);
            float mean = s * 0.0625f;
            float var = s2 * 0.0625f - mean * mean;
            float inv = rsqrtf(var + 1e-5f);
            q_ws[((size_t)(n * 4 + h) * TDIM + t) * 16 + c] = (y - mean) * inv * lnqw_c + lnqb_c;
        }
#pragma unroll
        for (int h = 0; h < 4; ++h) {
            float y = acc[4 + h][j];
            float s = y;  RED16(s);
            float s2 = y * y;  RED16(s2);
            float mean = s * 0.0625f;
            float var = s2 * 0.0625f - mean * mean;
            float inv = rsqrtf(var + 1e-5f);
            float kn = (y - mean) * inv * lnkw_c + lnkb_c;
            float s3 = kn * kn;  RED16(s3);
            kn = kn / fmaxf(sqrtf(s3), 1e-12f);
            k_ws[((size_t)(n * 4 + h) * TDIM + t) * 16 + c] = kn;
        }
#pragma unroll
        for (int h = 0; h < 4; ++h)
            v_ws[((size_t)(n * 4 + h) * TDIM + t) * 16 + c] = acc[8 + h][j];
        float yb = acc[12][j];
        if (c < 4) {
            float Kv = fminf(fabsf(curv[n >> 4]), 10.0f);
            beta_ws[(size_t)(n * 4 + c) * TDIM + t] = sigf(sigf(yb + Wbb[c]) + Kv * cw[c]);
        } else if (c < 8) {
            int h = c - 4;
            float Sv = fminf(fmaxf(ent[n >> 4], 0.0f), 5.0f);
            alpha_ws[(size_t)(n * 4 + h) * TDIM + t] = sigf(sigf(yb + Wab[h]) + Sv * ew[h]);
        }
    }
}

// ---------------------------------------------------------------------------
// Segmented scan. Recurrence is affine: M_t = M_{t-1} A_t + b_t with
// A_t = I - a k k^T, b_t = b v k^T. Per 128-step segment: M_out = M_in P + Q,
// P = prod A_t (16x16), Q = run-from-zero. Phase1 computes (P,Q) per segment
// via the same stale-reassociated row recurrence (P rows: beta=0, init I).
// Phase2 folds M_in across segments. Phase3 = original machinery primed with
// exact M_in (w1=w2=0 makes all cross-boundary table terms vanish).
// ---------------------------------------------------------------------------

// Phase 1: per (chain, segment 0..14) compute transfer (P,Q).
__global__ __launch_bounds__(64) void scan_p1_kernel(
    const float* __restrict__ k_ws, const float* __restrict__ v_ws,
    const float* __restrict__ beta_ws, const float* __restrict__ alpha_ws,
    float* __restrict__ pq_ws)
{
    __shared__ __align__(16) float ks[128 * 16], bvs[128 * 16];
    __shared__ __align__(16) float tb1[128 * 4];
    const int tid = threadIdx.x;
    const int sid = blockIdx.x;     // 0..14
    const int cid = blockIdx.y;     // 0..255
    const int i = tid & 15, g = tid >> 4;
    const int t0g = sid * SEGLEN;
    const float* kb = k_ws + ((size_t)cid * TDIM + t0g) * 16;
    const float* vb = v_ws + ((size_t)cid * TDIM + t0g) * 16;
    const float* bb = beta_ws + (size_t)cid * TDIM + t0g;
    const float* ab = alpha_ws + (size_t)cid * TDIM + t0g;

    for (int f = tid; f < 128 * 16; f += 64) { ks[f] = 0.f; bvs[f] = 0.f; }
    for (int f = tid; f < 128 * 4; f += 64) tb1[f] = 0.f;
    __syncthreads();

    float4 kr[4], vr[4]; float be = 0.f, alp = 0.f;
    auto load_stage = [&](int s) {
        size_t t0 = (size_t)s * 64 + tid;
        const float4* kp = (const float4*)(kb + t0 * 16);
        const float4* vp = (const float4*)(vb + t0 * 16);
#pragma unroll
        for (int j = 0; j < 4; ++j) { kr[j] = kp[j]; vr[j] = vp[j]; }
        be = bb[t0]; alp = ab[t0];
    };
    auto commit_stage = [&](int s) {
        int r = (s & 1) * 64 + tid;
#pragma unroll
        for (int j = 0; j < 4; ++j) {
            *(float4*)&ks[r * 16 + 4 * j] = kr[j];
            float4 bv4 = make_float4(be * vr[j].x, be * vr[j].y, be * vr[j].z, be * vr[j].w);
            *(float4*)&bvs[r * 16 + 4 * j] = bv4;
        }
    };
    auto table_pass = [&](int s) {
        int r0 = (s & 1) * 64 + tid;
        int rm1 = (r0 - 1) & 127, rm2 = (r0 - 2) & 127;
        float C = 0.f, C2 = 0.f;
#pragma unroll
        for (int j = 0; j < 4; ++j) {
            float4 kt  = *(float4*)&ks[r0 * 16 + 4 * j];
            float4 km1 = *(float4*)&ks[rm1 * 16 + 4 * j];
            float4 km2 = *(float4*)&ks[rm2 * 16 + 4 * j];
            C  += dot4f(km1, kt);
            C2 += dot4f(km2, kt);
        }
        *(float4*)&tb1[r0 * 4] = make_float4(alp * C, alp * C2, alp, 0.f);
    };

    load_stage(0);
    commit_stage(0);
    __syncthreads();
    table_pass(0);
    __syncthreads();

    // dual state: Q rows (init 0, source bv), P rows (init I, source 0)
    float4 Q4 = make_float4(0.f, 0.f, 0.f, 0.f);
    float4 P4 = make_float4(i == 4 * g + 0 ? 1.f : 0.f,
                            i == 4 * g + 1 ? 1.f : 0.f,
                            i == 4 * g + 2 ? 1.f : 0.f,
                            i == 4 * g + 3 ? 1.f : 0.f);
    float wq1 = 0.f, wq2 = 0.f, wp1 = 0.f, wp2 = 0.f;
    float4 k4m1 = make_float4(0.f, 0.f, 0.f, 0.f);
    float4 k4_0 = *(float4*)&ks[0 * 16 + 4 * g];
    float4 k4p1 = *(float4*)&ks[1 * 16 + 4 * g];
    float upQ_cur = 0.f;                 // 0 . k0
    float upP_cur = ks[i];               // (I k0)[i] = k0[i]
    float4 ta0 = *(float4*)&tb1[0];
    float aC1_c = ta0.x, aC2_c = ta0.y, al_c = ta0.z;
    float bv_c = bvs[i];

    int t = 0;
    auto step = [&]() {
        int rp2 = (t + 2) & 127, rp1 = (t + 1) & 127;
        float4 k4in = *(float4*)&ks[rp2 * 16 + 4 * g];
        float4 tain = *(float4*)&tb1[rp1 * 4];
        float bvin = bvs[rp1 * 16 + i];
        float upQ = red4g(dot4f(Q4, k4p1));
        float upP = red4g(dot4f(P4, k4p1));
        Q4.x = fmaf(wq1, k4m1.x, Q4.x);
        Q4.y = fmaf(wq1, k4m1.y, Q4.y);
        Q4.z = fmaf(wq1, k4m1.z, Q4.z);
        Q4.w = fmaf(wq1, k4m1.w, Q4.w);
        P4.x = fmaf(wp1, k4m1.x, P4.x);
        P4.y = fmaf(wp1, k4m1.y, P4.y);
        P4.z = fmaf(wp1, k4m1.z, P4.z);
        P4.w = fmaf(wp1, k4m1.w, P4.w);
        float rq = fmaf(-aC2_c, wq2, fmaf(-al_c, upQ_cur, bv_c));
        float wq0 = fmaf(-aC1_c, wq1, rq);
        float rp_ = fmaf(-aC2_c, wp2, -al_c * upP_cur);
        float wp0 = fmaf(-aC1_c, wp1, rp_);
        wq2 = wq1; wq1 = wq0; wp2 = wp1; wp1 = wp0;
        k4m1 = k4_0; k4_0 = k4p1; k4p1 = k4in;
        upQ_cur = upQ; upP_cur = upP;
        aC1_c = tain.x; aC2_c = tain.y; al_c = tain.z; bv_c = bvin;
        ++t;
    };

    // chunk 0 (with stage-1 prefetch), then chunk 1 (no further staging;
    // the final 2 steps' look-ahead reads hit stale rows but feed only
    // discarded pipeline state — all finite).
    load_stage(1);
#pragma unroll 4
    for (int u = 0; u < 32; ++u) step();
    commit_stage(1);
#pragma unroll 4
    for (int u = 0; u < 16; ++u) step();
    table_pass(1);
#pragma unroll 4
    for (int u = 0; u < 16; ++u) step();
#pragma unroll 4
    for (int u = 0; u < 64; ++u) step();

    // finalize lag: state = M_{126}; add w_{127} k_{127}
    Q4.x = fmaf(wq1, k4m1.x, Q4.x);
    Q4.y = fmaf(wq1, k4m1.y, Q4.y);
    Q4.z = fmaf(wq1, k4m1.z, Q4.z);
    Q4.w = fmaf(wq1, k4m1.w, Q4.w);
    P4.x = fmaf(wp1, k4m1.x, P4.x);
    P4.y = fmaf(wp1, k4m1.y, P4.y);
    P4.z = fmaf(wp1, k4m1.z, P4.z);
    P4.w = fmaf(wp1, k4m1.w, P4.w);

    float* dst = pq_ws + ((size_t)cid * 15 + sid) * 512;
    *(float4*)&dst[i * 16 + 4 * g] = Q4;
    *(float4*)&dst[256 + i * 16 + 4 * g] = P4;
}

// Phase 2: fold M_in across segments: M <- M P_s + Q_s, store per-segment M_in.
__global__ __launch_bounds__(64) void scan_p2_kernel(
    const float* __restrict__ pq_ws, float* __restrict__ min_ws)
{
    __shared__ float Mlds[256], Plds[256];
    const int tid = threadIdx.x;
    const int cid = blockIdx.x;
    const int i = tid & 15, g = tid >> 4;
    float4 M4 = make_float4(0.f, 0.f, 0.f, 0.f);
    *(float4*)&min_ws[((size_t)cid * SEG + 0) * 256 + i * 16 + 4 * g] = M4;
    for (int sid = 0; sid < 15; ++sid) {
        const float* base = pq_ws + ((size_t)cid * 15 + sid) * 512;
        float4 Qn = *(const float4*)&base[i * 16 + 4 * g];
        float4 Pn = *(const float4*)&base[256 + i * 16 + 4 * g];
        *(float4*)&Mlds[i * 16 + 4 * g] = M4;
        *(float4*)&Plds[i * 16 + 4 * g] = Pn;
        __syncthreads();
        float4 acc = Qn;
#pragma unroll
        for (int m = 0; m < 16; ++m) {
            float mm = Mlds[i * 16 + m];
            float4 pr = *(float4*)&Plds[m * 16 + 4 * g];
            acc.x = fmaf(mm, pr.x, acc.x);
            acc.y = fmaf(mm, pr.y, acc.y);
            acc.z = fmaf(mm, pr.z, acc.z);
            acc.w = fmaf(mm, pr.w, acc.w);
        }
        M4 = acc;
        __syncthreads();
        *(float4*)&min_ws[((size_t)cid * SEG + sid + 1) * 256 + i * 16 + 4 * g] = M4;
    }
}

// Phase 3: original delta-rule machinery per (chain, segment), primed with
// exact M_in. w1=w2=0 at entry: cross-boundary C/C2/e/E2 terms are x0.
__global__ __launch_bounds__(64) void scan_p3_kernel(
    const float* __restrict__ q_ws, const float* __restrict__ k_ws, const float* __restrict__ v_ws,
    const float* __restrict__ beta_ws, const float* __restrict__ alpha_ws,
    const float* __restrict__ min_ws, float* __restrict__ o_ws)
{
    __shared__ __align__(16) float ks[128 * 16], qs[128 * 16], bvs[128 * 16];
    __shared__ __align__(16) float tbl[128 * 8];
    __shared__ __align__(16) float os[64 * 16];
    const int tid = threadIdx.x;
    const int sid = blockIdx.x;     // 0..15
    const int cid = blockIdx.y;     // 0..255
    const int i = tid & 15, g = tid >> 4;
    const int t0g = sid * SEGLEN;
    const float* kb = k_ws + ((size_t)cid * TDIM + t0g) * 16;
    const float* qb = q_ws + ((size_t)cid * TDIM + t0g) * 16;
    const float* vb = v_ws + ((size_t)cid * TDIM + t0g) * 16;
    const float* bb = beta_ws + (size_t)cid * TDIM + t0g;
    const float* ab = alpha_ws + (size_t)cid * TDIM + t0g;
    float* obp = o_ws + ((size_t)cid * TDIM + t0g) * 16;

    for (int f = tid; f < 128 * 16; f += 64) { ks[f] = 0.f; qs[f] = 0.f; bvs[f] = 0.f; }
    for (int f = tid; f < 128 * 8; f += 64) tbl[f] = 0.f;
    __syncthreads();

    float4 kr[4], qr[4], vr[4]; float be = 0.f, alp = 0.f;
    auto load_stage = [&](int s) {
        size_t t0 = (size_t)s * 64 + tid;   // overrun past segment stays in ws
        const float4* kp = (const float4*)(kb + t0 * 16);
        const float4* qp = (const float4*)(qb + t0 * 16);
        const float4* vp = (const float4*)(vb + t0 * 16);
#pragma unroll
        for (int j = 0; j < 4; ++j) { kr[j] = kp[j]; qr[j] = qp[j]; vr[j] = vp[j]; }
        be = bb[t0]; alp = ab[t0];
    };
    auto commit_stage = [&](int s) {
        int r = (s & 1) * 64 + tid;
#pragma unroll
        for (int j = 0; j < 4; ++j) {
            *(float4*)&ks[r * 16 + 4 * j] = kr[j];
            *(float4*)&qs[r * 16 + 4 * j] = qr[j];
            float4 bv4 = make_float4(be * vr[j].x, be * vr[j].y, be * vr[j].z, be * vr[j].w);
            *(float4*)&bvs[r * 16 + 4 * j] = bv4;
        }
    };
    auto table_pass = [&](int s) {
        int r0 = (s & 1) * 64 + tid;
        int rm1 = (r0 - 1) & 127, rm2 = (r0 - 2) & 127;
        float C = 0.f, C2 = 0.f, d = 0.f, e = 0.f, E2 = 0.f;
#pragma unroll
        for (int j = 0; j < 4; ++j) {
            float4 kt  = *(float4*)&ks[r0 * 16 + 4 * j];
            float4 km1 = *(float4*)&ks[rm1 * 16 + 4 * j];
            float4 km2 = *(float4*)&ks[rm2 * 16 + 4 * j];
            float4 qt  = *(float4*)&qs[r0 * 16 + 4 * j];
            C  += dot4f(km1, kt);
            C2 += dot4f(km2, kt);
            d  += dot4f(kt,  qt);
            e  += dot4f(km1, qt);
            E2 += dot4f(km2, qt);
        }
        *(float4*)&tbl[r0 * 8] = make_float4(alp * C, alp * C2, d, e);
        *(float2*)&tbl[r0 * 8 + 4] = make_float2(E2, alp);
    };

    load_stage(0);
    commit_stage(0);
    __syncthreads();
    table_pass(0);
    __syncthreads();

    // prime with exact M_in = M_{t0-1}
    float4 M4 = *(const float4*)&min_ws[((size_t)cid * SEG + sid) * 256 + i * 16 + 4 * g];
    float w1 = 0.f, w2 = 0.f;
    float4 k4m1 = make_float4(0.f, 0.f, 0.f, 0.f);
    float4 k4_0 = *(float4*)&ks[0 * 16 + 4 * g];
    float4 q4_0 = *(float4*)&qs[0 * 16 + 4 * g];
    float4 k4p1 = *(float4*)&ks[1 * 16 + 4 * g];
    float4 q4p1 = *(float4*)&qs[1 * 16 + 4 * g];
    float up_cur = red4g(dot4f(M4, k4_0));   // M_in . k_{t0}
    float rp_cur = red4g(dot4f(M4, q4_0));   // M_in . q_{t0}
    float4 ta0 = *(float4*)&tbl[0];
    float aC1_c = ta0.x, aC2_c = ta0.y, d_c = ta0.z, e_c = ta0.w;
    float2 tx0 = *(float2*)&tbl[4];
    float E2_c = tx0.x, al_c = tx0.y;
    float bv_c = bvs[i];

    int t = 0;
    auto step = [&]() {
        int rp2 = (t + 2) & 127, rp1 = (t + 1) & 127;
        float4 k4in = *(float4*)&ks[rp2 * 16 + 4 * g];
        float4 q4in = *(float4*)&qs[rp2 * 16 + 4 * g];
        float4 tain = *(float4*)&tbl[rp1 * 8];
        float2 txin = *(float2*)&tbl[rp1 * 8 + 4];
        float bvin = bvs[rp1 * 16 + i];
        float up = red4g(dot4f(M4, k4p1));
        float rp = red4g(dot4f(M4, q4p1));
        M4.x = fmaf(w1, k4m1.x, M4.x);
        M4.y = fmaf(w1, k4m1.y, M4.y);
        M4.z = fmaf(w1, k4m1.z, M4.z);
        M4.w = fmaf(w1, k4m1.w, M4.w);
        float r = fmaf(-aC2_c, w2, fmaf(-al_c, up_cur, bv_c));
        float w0 = fmaf(-aC1_c, w1, r);
        float o = fmaf(w0, d_c, fmaf(w1, e_c, fmaf(w2, E2_c, rp_cur)));
        if (g == 0) os[(t & 63) * 16 + i] = o;
        w2 = w1; w1 = w0;
        k4m1 = k4_0; k4_0 = k4p1; k4p1 = k4in;
        q4p1 = q4in;
        up_cur = up; rp_cur = rp;
        aC1_c = tain.x; aC2_c = tain.y; d_c = tain.z; e_c = tain.w;
        E2_c = txin.x; al_c = txin.y; bv_c = bvin;
        ++t;
    };

    for (int s = 0; s < 2; ++s) {
        if (s == 0) load_stage(1);
#pragma unroll 4
        for (int u = 0; u < 32; ++u) step();
        if (s == 0) commit_stage(1);
#pragma unroll 4
        for (int u = 0; u < 16; ++u) step();
        if (s == 0) table_pass(1);
#pragma unroll 4
        for (int u = 0; u < 16; ++u) step();
#pragma unroll
        for (int j = 0; j < 4; ++j) {
            float4 ov = *(float4*)&os[(tid * 4 + j) * 4];
            *(float4*)&obp[(size_t)s * 1024 + (tid * 4 + j) * 4] = ov;
        }
    }
}

// ---------------------------------------------------------------------------
// Kernel C: output projection (split-bf16 MFMA), W from pre-split image.
// ---------------------------------------------------------------------------
__global__ __launch_bounds__(256, 2) void outproj_kernel(
    const float* __restrict__ o_ws, const short* __restrict__ owimg,
    const float* __restrict__ ob, float* __restrict__ out)
{
    __shared__ __align__(16) short osh[64 * LROW];
    __shared__ __align__(16) short wsh[192 * LROW];
    const int tid = threadIdx.x;
    const int lane = tid & 63, wv = tid >> 6;
    const int row0 = blockIdx.x * 64;

    float4v acc[12];
#pragma unroll
    for (int cc = 0; cc < 12; ++cc) acc[cc] = (float4v){0.f, 0.f, 0.f, 0.f};

#pragma unroll
    for (int it = 0; it < 4; ++it) {
        int f = it * 256 + tid;
        int rr = f >> 4, c4 = f & 15;
        int grow = row0 + rr;
        int n = grow >> 11, t = grow & 2047;
        int h = c4 >> 2, d4 = c4 & 3;
        float4 xv = *(const float4*)&o_ws[((size_t)(n * 4 + h) * TDIM + t) * 16 + d4 * 4];
        short4v hi, lo;
        split4(xv, hi, lo);
        short* ph = &osh[rr * LROW + (c4 >> 1) * 16 + (c4 & 1) * 4];
        *(short4v*)ph = hi;
        *(short4v*)(ph + 8) = lo;
    }
    {
        const int4* wsrc = (const int4*)owimg;
#pragma unroll
        for (int it = 0; it < 12; ++it) {
            int f = it * 256 + tid;
            int4 tv = wsrc[f];
            int row = f >> 4, idx = f & 15;
            *(int4*)&wsh[row * LROW + (idx >> 1) * 16 + (idx & 1) * 8] = tv;
        }
    }
    __syncthreads();

#pragma unroll
    for (int ks = 0; ks < 2; ++ks) {
        const int rowA = wv * 16 + (lane & 15);
        const int g4 = ks * 4 + (lane >> 4);
        short8 ah = *(const short8*)&osh[rowA * LROW + g4 * 16];
        short8 al = *(const short8*)&osh[rowA * LROW + g4 * 16 + 8];
#pragma unroll
        for (int nt = 0; nt < 12; ++nt) {
            const int rowB = nt * 16 + (lane & 15);
            short8 bh = *(const short8*)&wsh[rowB * LROW + g4 * 16];
            short8 bl = *(const short8*)&wsh[rowB * LROW + g4 * 16 + 8];
            acc[nt] = __builtin_amdgcn_mfma_f32_16x16x32_bf16(ah, bh, acc[nt], 0, 0, 0);
            acc[nt] = __builtin_amdgcn_mfma_f32_16x16x32_bf16(ah, bl, acc[nt], 0, 0, 0);
            acc[nt] = __builtin_amdgcn_mfma_f32_16x16x32_bf16(al, bh, acc[nt], 0, 0, 0);
        }
    }

    const int c = lane & 15, lq = lane >> 4;
#pragma unroll
    for (int nt = 0; nt < 12; ++nt) {
        float bias = ob[nt * 16 + c];
#pragma unroll
        for (int j = 0; j < 4; ++j) {
            int grow = row0 + wv * 16 + lq * 4 + j;
            int n = grow >> 11, t = grow & 2047;
            int b = n >> 4, p = n & 15;
            out[((size_t)(b * TDIM + t) * 16 + p) * 192 + nt * 16 + c] = acc[nt][j] + bias;
        }
    }
}

extern "C" void kernel_launch(void* const* d_in, const int* in_sizes, int n_in,
                              void* d_out, int out_size, void* d_ws, size_t ws_size,
                              hipStream_t stream) {
    (void)in_sizes; (void)n_in; (void)out_size; (void)ws_size;
    const float* x    = (const float*)d_in[0];
    const float* curv = (const float*)d_in[1];
    const float* ent  = (const float*)d_in[2];
    const float* Wq   = (const float*)d_in[3];
    const float* Wk   = (const float*)d_in[4];
    const float* Wv   = (const float*)d_in[5];
    const float* Wbw  = (const float*)d_in[6];
    const float* Wbb  = (const float*)d_in[7];
    const float* Waw  = (const float*)d_in[8];
    const float* Wab  = (const float*)d_in[9];
    const float* cw   = (const float*)d_in[10];
    const float* ew   = (const float*)d_in[11];
    const float* ow   = (const float*)d_in[12];
    const float* ob   = (const float*)d_in[13];
    const float* lnqw = (const float*)d_in[14];
    const float* lnqb = (const float*)d_in[15];
    const float* lnkw = (const float*)d_in[16];
    const float* lnkb = (const float*)d_in[17];
    float* out = (float*)d_out;

    float* ws = (float*)d_ws;
    float* q_ws     = ws;                    // 8,388,608 floats
    float* k_ws     = q_ws + 8388608;
    float* v_ws     = k_ws + 8388608;
    float* beta_ws  = v_ws + 8388608;        // 524,288
    float* alpha_ws = beta_ws + 524288;
    float* o_ws     = alpha_ws + 524288;     // 8,388,608

    // Overlays: wimg at o_ws head (dead before scan writes o_ws); owimg at
    // q_ws head (written after scan). Segment scratch (P,Q and per-segment
    // M_in) lives at the head of d_out — dead until outproj runs.
    short* wimg  = (short*)o_ws;             // 106,496 shorts
    short* owimg = (short*)q_ws;             // 24,576 shorts
    float* pq_ws  = out;                     // 256*15*512 = 1,966,080 floats
    float* min_ws = out + 1966080;           // 256*16*256 = 1,048,576 floats

    prep_w_kernel<<<26, 256, 0, stream>>>(Wq, Wk, Wv, Wbw, Waw, wimg);
    proj_kernel<<<2048, 256, 0, stream>>>(x, curv, ent, wimg, Wbb, Wab,
                                          cw, ew, lnqw, lnqb, lnkw, lnkb,
                                          q_ws, k_ws, v_ws, beta_ws, alpha_ws);
    scan_p1_kernel<<<dim3(15, 256), 64, 0, stream>>>(k_ws, v_ws, beta_ws, alpha_ws, pq_ws);
    scan_p2_kernel<<<256, 64, 0, stream>>>(pq_ws, min_ws);
    scan_p3_kernel<<<dim3(16, 256), 64, 0, stream>>>(q_ws, k_ws, v_ws, beta_ws, alpha_ws,
                                                     min_ws, o_ws);
    prep_ow_kernel<<<6, 256, 0, stream>>>(ow, owimg);
    outproj_kernel<<<2048, 256, 0, stream>>>(o_ws, owimg, ob, out);
}